// Round 1
// 332.974 us; speedup vs baseline: 1.0158x; 1.0158x over previous
//
#include <hip/hip_runtime.h>
#include <cstdint>
#include <cstddef>

// Problem constants (fixed by reference):
#define NSLOTS 16
#define DIM    256        // SLOT_DIM = FEAT_DIM = K = N of both GEMMs
#define FEAT   4096
#define MT     128        // rows per GEMM block tile
#define LDA    264        // Abuf row stride in bf16 elements (+8 pad: 528B rows -> 2-way bank alias, free)

typedef __attribute__((ext_vector_type(8))) short    short8;   // 8 bf16 bit-patterns (4 VGPRs)
typedef __attribute__((ext_vector_type(4))) float    floatx4;  // MFMA accumulator
typedef __attribute__((ext_vector_type(4))) unsigned uintx4;   // 8 packed bf16

// v_cvt_pk_bf16_f32: 2 f32 -> 1 dword of 2 bf16, round-to-nearest-even
// (identical rounding to the old manual f2bf, 1 instr instead of ~4).
// No builtin on gfx950 (learn_hip m240) -> inline asm.
__device__ __forceinline__ unsigned cvt_pk_bf16(float lo, float hi) {
    unsigned r;
    asm("v_cvt_pk_bf16_f32 %0, %1, %2" : "=v"(r) : "v"(lo), "v"(hi));
    return r;
}

// ---------------------------------------------------------------------------
// Kernel 1: prep = W-swizzle (blocks 0..63) + mask argmax (blocks 64..1087).
//
// Swizzle: W1/W2 (fp32 [K=256][N=256] row-major) -> bf16 MFMA B-fragment order:
//   Ws[((kt*16+nt)*64+lane)*8 + j] = W[kt*32 + (lane>>4)*8 + j][nt*16 + (lane&15)]
// so each lane's B fragment for (kt,nt) is one coalesced 16-B load.
//
// Argmax: idx[b,f] = first argmax over the 16 slots (uint8). Hoisting this off
// fused_main's critical path removes a 6-idle-wave serial phase + one barrier.
// ---------------------------------------------------------------------------
__global__ __launch_bounds__(256) void prep_kernel(
        const float* __restrict__ W1, const float* __restrict__ W2,
        const float* __restrict__ mask,
        short* __restrict__ W1s, short* __restrict__ W2s,
        unsigned char* __restrict__ Idx) {
    int bid = blockIdx.x;
    int tid = threadIdx.x;
    if (bid < 64) {
        int t = bid * 256 + tid;                 // 16384 swizzle threads
        int lane = t & 63;
        int nt   = (t >> 6) & 15;
        int kt   = (t >> 10) & 7;
        int m    = t >> 13;
        const float* W  = m ? W2 : W1;
        short*       Ws = m ? W2s : W1s;
        int n  = nt * 16 + (lane & 15);
        int kb = kt * 32 + (lane >> 4) * 8;
        float v[8];
#pragma unroll
        for (int j = 0; j < 8; ++j)
            v[j] = W[(size_t)(kb + j) * DIM + n];
        uintx4 hv;
#pragma unroll
        for (int j = 0; j < 4; ++j)
            hv[j] = cvt_pk_bf16(v[2 * j], v[2 * j + 1]);
        *(uintx4*)(Ws + ((size_t)((kt * 16 + nt) * 64 + lane)) * 8) = hv;
    } else {
        int t = bid - 64;                        // 0..1023, 256 f's each
        int b = t >> 4;
        int f = ((t & 15) << 8) + tid;
        const float* mp = mask + (size_t)b * NSLOTS * FEAT + f;
        float best = mp[0];
        int bi = 0;
#pragma unroll
        for (int s = 1; s < NSLOTS; ++s) {       // strict > keeps FIRST max (jnp.argmax)
            float v = mp[(size_t)s * FEAT];
            if (v > best) { best = v; bi = s; }
        }
        Idx[(size_t)b * FEAT + f] = (unsigned char)bi;
    }
}

// ---------------------------------------------------------------------------
// Shared MFMA core: Abuf[128 rows x 256 k] (bf16, stride LDA) times Ws (swizzled
// 256x256 bf16), 512 threads = 8 waves in 2 (m) x 4 (n) arrangement.
// Each wave: 4x4 tiles of 16x16, acc 64 VGPRs.
// ---------------------------------------------------------------------------
__device__ __forceinline__ void mfma_core(const short* Abuf,
                                          const short* __restrict__ Ws,
                                          int tid, floatx4 acc[4][4]) {
    int lane = tid & 63;
    int w    = tid >> 6;
    int m_base = (w >> 2) * 64;
    int ng     = (w & 3) * 4;            // first n-tile index (16-col tiles)
    int arow   = lane & 15;
    int ak     = (lane >> 4) * 8;
#pragma unroll
    for (int kt = 0; kt < 8; ++kt) {
        short8 a[4], b[4];
#pragma unroll
        for (int mt = 0; mt < 4; ++mt)
            a[mt] = *(const short8*)(Abuf + (m_base + mt * 16 + arow) * LDA + kt * 32 + ak);
#pragma unroll
        for (int nt = 0; nt < 4; ++nt)
            b[nt] = *(const short8*)(Ws + ((size_t)((kt * 16 + ng + nt) * 64 + lane)) * 8);
#pragma unroll
        for (int mt = 0; mt < 4; ++mt)
#pragma unroll
            for (int nt = 0; nt < 4; ++nt)
                acc[mt][nt] = __builtin_amdgcn_mfma_f32_16x16x32_bf16(
                    a[mt], b[nt], acc[mt][nt], 0, 0, 0);
    }
}

// ---------------------------------------------------------------------------
// Kernel 2: precompute S1 = slots@W1 + b1 (rows 0..1023) and P1 = pos_embed@W1
// (rows 1024..5119), fp32 output into workspace. 40 blocks x 512 threads.
// ---------------------------------------------------------------------------
__global__ __launch_bounds__(512) void precompute_kernel(
        const float* __restrict__ slots, const float* __restrict__ pos,
        const float* __restrict__ b1, const short* __restrict__ W1s,
        float* __restrict__ S1P1) {
    __shared__ short Abuf[MT * LDA];
    int tid  = threadIdx.x;
    int row0 = blockIdx.x * MT;          // [0, 5120); 1024 % 128 == 0 so a block is all-slots or all-pos
#pragma unroll
    for (int p = 0; p < 8; ++p) {
        int v   = tid + p * 512;         // 0..4095 -> (row, k-octet)
        int row = v >> 5;
        int k0  = (v & 31) * 8;
        int gr  = row0 + row;
        const float* src = (gr < 1024) ? (slots + (size_t)gr * DIM + k0)
                                       : (pos + (size_t)(gr - 1024) * DIM + k0);
        floatx4 a0 = *(const floatx4*)src;
        floatx4 a1 = *(const floatx4*)(src + 4);
        uintx4 hv;
        hv[0] = cvt_pk_bf16(a0[0], a0[1]);
        hv[1] = cvt_pk_bf16(a0[2], a0[3]);
        hv[2] = cvt_pk_bf16(a1[0], a1[1]);
        hv[3] = cvt_pk_bf16(a1[2], a1[3]);
        *(uintx4*)(Abuf + row * LDA + k0) = hv;
    }
    __syncthreads();

    floatx4 acc[4][4];
#pragma unroll
    for (int mt = 0; mt < 4; ++mt)
#pragma unroll
        for (int nt = 0; nt < 4; ++nt)
            acc[mt][nt] = floatx4{0.f, 0.f, 0.f, 0.f};
    mfma_core(Abuf, W1s, tid, acc);

    int lane = tid & 63, w = tid >> 6;
    int m_base = (w >> 2) * 64, n_base = (w & 3) * 64;
    bool isSlots = (row0 < 1024);
#pragma unroll
    for (int nt = 0; nt < 4; ++nt) {
        int col = n_base + nt * 16 + (lane & 15);
        float bias = isSlots ? b1[col] : 0.f;
#pragma unroll
        for (int mt = 0; mt < 4; ++mt) {
            size_t r0 = (size_t)row0 + m_base + mt * 16 + (lane >> 4) * 4;
#pragma unroll
            for (int r = 0; r < 4; ++r)
                S1P1[(r0 + r) * DIM + col] = acc[mt][nt][r] + bias;
        }
    }
}

// ---------------------------------------------------------------------------
// Kernel 3: fused main. Per 128-row tile (one b, 128 consecutive f):
//   h = relu(S1[b,Idx[row]] + P1[f]) as bf16 in LDS -> MFMA vs W2 -> +b2 -> fp32.
// __launch_bounds__(512,4): cap at 128 VGPR so 2 blocks (16 waves) co-reside
// per CU -> block B's MFMA/store overlaps block A's staging. LDS = 68 KB/block
// (2 fit in 160 KB). Single barrier (argmax precomputed; idx read is a
// broadcast L2 byte load per 32-thread row group).
// ---------------------------------------------------------------------------
__global__ __launch_bounds__(512, 4) void fused_main_kernel(
        const float* __restrict__ b2, const float* __restrict__ S1P1,
        const short* __restrict__ W2s, const unsigned char* __restrict__ Idx,
        float* __restrict__ out) {
    __shared__ short Abuf[MT * LDA];
    int tid  = threadIdx.x;
    int row0 = blockIdx.x * MT;          // global output row = b*4096 + f
    int b    = row0 >> 12;

    // build h tile: relu(S1[b, idx[row]] + P1[f0+row]) -> bf16 into LDS
    const float* P1 = S1P1 + (size_t)1024 * DIM;
#pragma unroll
    for (int p = 0; p < 8; ++p) {
        int v   = tid + p * 512;
        int row = v >> 5;
        int k0  = (v & 31) * 8;
        int s   = Idx[row0 + row];       // Idx is [b][f] flat == global row index
        const floatx4* s1 = (const floatx4*)(S1P1 + ((size_t)(b * NSLOTS + s)) * DIM + k0);
        const floatx4* p1 = (const floatx4*)(P1 + (size_t)(row0 - (size_t)b * FEAT + row) * DIM + k0);
        floatx4 x0 = s1[0] + p1[0];
        floatx4 x1 = s1[1] + p1[1];
        uintx4 hv;
        hv[0] = cvt_pk_bf16(fmaxf(x0[0], 0.f), fmaxf(x0[1], 0.f));
        hv[1] = cvt_pk_bf16(fmaxf(x0[2], 0.f), fmaxf(x0[3], 0.f));
        hv[2] = cvt_pk_bf16(fmaxf(x1[0], 0.f), fmaxf(x1[1], 0.f));
        hv[3] = cvt_pk_bf16(fmaxf(x1[2], 0.f), fmaxf(x1[3], 0.f));
        *(uintx4*)(Abuf + row * LDA + k0) = hv;
    }
    __syncthreads();

    floatx4 acc[4][4];
#pragma unroll
    for (int mt = 0; mt < 4; ++mt)
#pragma unroll
        for (int nt = 0; nt < 4; ++nt)
            acc[mt][nt] = floatx4{0.f, 0.f, 0.f, 0.f};
    mfma_core(Abuf, W2s, tid, acc);

    // epilogue: + b2, store fp32 (4 x 64B cache-line segments per store group)
    int lane = tid & 63, w = tid >> 6;
    int m_base = (w >> 2) * 64, n_base = (w & 3) * 64;
#pragma unroll
    for (int nt = 0; nt < 4; ++nt) {
        int col = n_base + nt * 16 + (lane & 15);
        float bias = b2[col];
#pragma unroll
        for (int mt = 0; mt < 4; ++mt) {
            size_t r0 = (size_t)row0 + m_base + mt * 16 + (lane >> 4) * 4;
            float* op = out + r0 * DIM + col;
#pragma unroll
            for (int r = 0; r < 4; ++r)
                op[(size_t)r * DIM] = acc[mt][nt][r] + bias;
        }
    }
}

// ---------------------------------------------------------------------------
extern "C" void kernel_launch(void* const* d_in, const int* in_sizes, int n_in,
                              void* d_out, int out_size, void* d_ws, size_t ws_size,
                              hipStream_t stream) {
    const float* slots = (const float*)d_in[0];  // [64,16,256]
    const float* mask  = (const float*)d_in[1];  // [64,16,4096]
    const float* pos   = (const float*)d_in[2];  // [1,4096,256]
    const float* W1    = (const float*)d_in[3];  // [256,256]
    const float* b1    = (const float*)d_in[4];  // [256]
    const float* W2    = (const float*)d_in[5];  // [256,256]
    const float* b2    = (const float*)d_in[6];  // [256]
    float* out = (float*)d_out;                  // [64,4096,256] fp32

    // workspace: S1P1 fp32 [5120*256] (5 MB) | W1s bf16 64K | W2s bf16 64K | Idx u8 256K
    char* ws = (char*)d_ws;
    float* S1P1 = (float*)ws;
    short* W1s  = (short*)(ws + (size_t)5120 * 256 * 4);
    short* W2s  = W1s + 65536;
    unsigned char* Idx = (unsigned char*)(W2s + 65536);

    prep_kernel<<<1088, 256, 0, stream>>>(W1, W2, mask, W1s, W2s, Idx);
    precompute_kernel<<<40, 512, 0, stream>>>(slots, pos, b1, W1s, S1P1);
    fused_main_kernel<<<2048, 512, 0, stream>>>(b2, S1P1, W2s, Idx, out);
}